// Round 5
// baseline (149.858 us; speedup 1.0000x reference)
//
#include <hip/hip_runtime.h>
#include <math.h>

// Problem constants (from reference): N=256, B=8, S=14, PILOTS=[0,7], U=1
static constexpr int kN   = 256;
static constexpr int kB   = 8;
static constexpr int kS   = 14;
static constexpr int kNSH = 12;   // S - len(PILOTS)
static constexpr int kBS  = kB * kS;  // 112

// ---------------------------------------------------------------------------
// Fused kernel: out[b,s,n] = sum_m cov[c(b,s), n, m] * h[b,s,m]  where
//   h[b,s,k] = DFT(x[b,s,:])[k] * conj(zc[k])
// Derivation: h_freq_est (pre-einsum) == fft(x, axis=-1) * conj(zc):
//   fft(ifft_ortho(zc)) = sqrt(N)*zc; the sqrt(N) cancels the /sqrt(N);
//   fft(ifft(Y)) == Y with default numpy norms.
// Output layout: PLANAR — real plane (B*S*N floats) then imag plane.
//
// Grid: 8 blocks per (b,s) = 896 blocks, 256 thr = 4 waves. Ordering within
// a block is latency-engineered:
//   1. issue x-row loads (2 dwords/thread)
//   2. issue all 16 cov float4 loads (16 KB/wave in flight — MLP)
//   3. compute the 256-pt DFT twiddle-recurrence (hides behind cov loads)
//   4. stage h through LDS, read lane fragments
//   5. complex FMA + 6-level butterfly (interleaved over 8 rows) + store
// The 8x-redundant DFT (~6 us VALU/CU grid-wide) overlaps the ~9 us cov
// HBM stream (57.3 MB, L3-cold each replay because the harness's 268 MB ws
// poison evicts L3), so the kernel stays memory-bound.
// ---------------------------------------------------------------------------
__global__ __launch_bounds__(256) void fused_kernel(
    const float* __restrict__ xr, const float* __restrict__ xi,
    const float* __restrict__ covr, const float* __restrict__ covi,
    const float* __restrict__ zcr, const float* __restrict__ zci,
    const int*  __restrict__ shift, const int* __restrict__ gidx,
    float* __restrict__ out)
{
    __shared__ float sxr[kN];
    __shared__ float sxi[kN];
    __shared__ float shr[kN];
    __shared__ float shi[kN];

    const int bs = blockIdx.x >> 3;     // (b*S + s), 0..111
    const int o  = blockIdx.x & 7;      // row octant 0..7
    const int s  = bs % kS;
    const int b  = bs / kS;

    const int tid = threadIdx.x;        // 0..255
    const int w   = tid >> 6;           // wave 0..3
    const int l   = tid & 63;           // lane

    // ---- 1. x-row loads (needed soonest) ----
    const float xre = xr[bs * kN + tid];
    const float xim = xi[bs * kN + tid];

    // complete[b,s]: padded-zero column 0 gathered; gidx==0 -> index 0,
    // else shift_val[b, gidx-1]
    const int g = gidx[s];
    const int c = (g == 0) ? 0 : shift[b * kNSH + (g - 1)];

    // ---- 2. cov loads: all 16 float4 issued before the DFT ----
    const long base = (long)c * (long)(kN * kN);
    const float* __restrict__ rb = covr + base;
    const float* __restrict__ ib = covi + base;
    const int n0 = o * 32 + w * 8;      // this wave's first row

    float4 mr[8], mi[8];
    #pragma unroll
    for (int r = 0; r < 8; ++r) {
        mr[r] = ((const float4*)(rb + (long)(n0 + r) * kN))[l];
        mi[r] = ((const float4*)(ib + (long)(n0 + r) * kN))[l];
    }

    // ---- 3. DFT of x (k = tid), twiddle recurrence, re-seeded per 32 ----
    sxr[tid] = xre;
    sxi[tid] = xim;

    const float two_pi_over_N = 6.283185307179586476925f / (float)kN;
    float wi_, wr_;
    sincosf(-two_pi_over_N * (float)tid, &wi_, &wr_); // w = e^{-2*pi*i*k/N}

    __syncthreads();

    float Hr = 0.0f, Hi = 0.0f;
    for (int m0 = 0; m0 < kN; m0 += 32) {
        // exact integer phase reduction: cur = e^{-2*pi*i*((k*m0) mod N)/N}
        const int p = (tid * m0) & (kN - 1);
        float ci_, cr_;
        sincosf(-two_pi_over_N * (float)p, &ci_, &cr_);
        #pragma unroll
        for (int j = 0; j < 32; ++j) {
            const int m = m0 + j;
            const float a  = sxr[m];   // wave-uniform broadcast (free)
            const float bb = sxi[m];
            Hr = fmaf(a, cr_, fmaf(-bb, ci_, Hr));
            Hi = fmaf(a, ci_, fmaf( bb, cr_, Hi));
            const float nr = cr_ * wr_ - ci_ * wi_;
            const float ni = cr_ * wi_ + ci_ * wr_;
            cr_ = nr; ci_ = ni;
        }
    }

    // h = H * conj(zc) -> stage to LDS
    const float zr = zcr[tid], zi = zci[tid];
    shr[tid] = fmaf(Hr, zr,  Hi * zi);
    shi[tid] = fmaf(Hi, zr, -Hr * zi);
    __syncthreads();

    // ---- 4. lane fragment: m = l*4 + j ----
    const float4 hr = ((const float4*)shr)[l];
    const float4 hi = ((const float4*)shi)[l];

    // ---- 5. complex dot partials, butterfly, store ----
    float ar[8], ai[8];
    #pragma unroll
    for (int r = 0; r < 8; ++r) {
        ar[r] = mr[r].x*hr.x + mr[r].y*hr.y + mr[r].z*hr.z + mr[r].w*hr.w
              - (mi[r].x*hi.x + mi[r].y*hi.y + mi[r].z*hi.z + mi[r].w*hi.w);
        ai[r] = mr[r].x*hi.x + mr[r].y*hi.y + mr[r].z*hi.z + mr[r].w*hi.w
              +  mi[r].x*hr.x + mi[r].y*hr.y + mi[r].z*hr.z + mi[r].w*hr.w;
    }

    #pragma unroll
    for (int off = 32; off > 0; off >>= 1) {
        #pragma unroll
        for (int r = 0; r < 8; ++r) {
            ar[r] += __shfl_xor(ar[r], off, 64);
            ai[r] += __shfl_xor(ai[r], off, 64);
        }
    }

    if (l == 0) {
        #pragma unroll
        for (int r = 0; r < 8; ++r) {
            // PLANAR complex layout: [Re plane | Im plane]
            out[(long)bs * kN + n0 + r]                    = ar[r];
            out[(long)(kBS * kN) + (long)bs * kN + n0 + r] = ai[r];
        }
    }
}

extern "C" void kernel_launch(void* const* d_in, const int* in_sizes, int n_in,
                              void* d_out, int out_size, void* d_ws, size_t ws_size,
                              hipStream_t stream) {
    const float* xr    = (const float*)d_in[0];  // (B,S,N)
    const float* xi    = (const float*)d_in[1];  // (B,S,N)
    const float* covr  = (const float*)d_in[2];  // (N,N,N)
    const float* covi  = (const float*)d_in[3];  // (N,N,N)
    const float* zcr   = (const float*)d_in[4];  // (N,)
    const float* zci   = (const float*)d_in[5];  // (N,)
    const int*   shift = (const int*)d_in[6];    // (B, S-2)
    const int*   gidx  = (const int*)d_in[7];    // (S,)

    (void)d_ws; (void)ws_size;

    fused_kernel<<<kBS * 8, 256, 0, stream>>>(xr, xi, covr, covi, zcr, zci,
                                              shift, gidx, (float*)d_out);
}